// Round 6
// baseline (251.500 us; speedup 1.0000x reference)
//
#include <hip/hip_runtime.h>
#include <math.h>

// ProtoLoss: loss = mean_n( -2*sim[n,fam[n]] + logsumexp_f(4*sim[n,f]) )
// sim = (e.p)/(||e||*||p||) -- scale-invariant in p: p_hat = raw_sum/||raw_sum||.
// N=262144, D=128, F=64.
//
// Session ledger:
//  - LDS fp32 atomics: ~0.3 lane-ops/cyc/CU -> any per-element-atomic segment
//    sum floors at ~150us (r1/r3).
//  - Two 512MB harness poison-fills (~77us each) sit INSIDE the timed window:
//    ~154us of dur_us is untouchable (r0/r5 top-5).
//  - Segment-sum-as-MFMA with one-hot A (bf16-exact) + hi/lo bf16 split of
//    emb is fp32-exact to ~2^-16: absmax 0.0 (r4/r5).
//  - r4 spill lesson: keep accumulator <= 32 VGPRs (acc[4][8] spilled ->
//    301MB scratch writes).
//
// A) 1024 blocks x 256 thr (4 blk/CU, 16 waves/CU). Wave w owns dim-slice
//    [32w,32w+32) for the block's 256 rows -> acc[4][2] = 32 VGPRs, no LDS,
//    no barrier. Per 32-row K-slab: 8 fam dwords, one-hot A words, emb
//    gathers (64B segments), hi/lo via pure bit-trunc word packing
//    (lo = x - trunc_bf16(x) is Sterbenz-exact; trunc(lo) err <= 2^-16|x|),
//    16 MFMA. Direct reg->psum stores.
// B) 64 blocks x 1024 thr: reduce 1024 partials + normalize -> protoB bf16;
//    block 0 zeroes d_out (stream-ordered before pass_c).
// C) swapped-operand MFMA sims + fused lse epilogue; one unsafeAtomicAdd
//    per block (r1->r2 A/B: same-address f32 atomics at block-end are free).

#define D_DIM 128
#define F_NUM 64
#define ROWS_A 256

typedef __attribute__((ext_vector_type(8))) short short8;
typedef __attribute__((ext_vector_type(4))) float f32x4;
typedef union { short8 s; unsigned u[4]; } pack8;

static __device__ __forceinline__ unsigned short f2bf(float x) {
  union { float f; unsigned u; } v; v.f = x;
  unsigned r = v.u + 0x7FFFu + ((v.u >> 16) & 1u);   // RNE
  return (unsigned short)(r >> 16);
}

// ---------------- Pass A -----------------------------------------------------
__global__ __launch_bounds__(256, 4) void pass_a(
    const float* __restrict__ emb, const int* __restrict__ fam,
    float* __restrict__ psum)
{
  int t = threadIdx.x, w = t >> 6, lane = t & 63;
  int m16 = lane & 15, q = lane >> 4;
  int dimBase = w * 32;                      // wave's private dim slice

  f32x4 acc[4][2] = {};                      // [f-tile][dim-tile] = 32 VGPRs
  int rb0 = blockIdx.x * ROWS_A;

  #pragma unroll 2
  for (int s = 0; s < ROWS_A / 32; ++s) {
    int rb = rb0 + s * 32;                   // K-slab of 32 rows
    // fam for this lane's k-slots: k = q*8 + j (verified A convention)
    const int* fp = fam + rb + q * 8;
    int fj[8];
    #pragma unroll
    for (int j = 0; j < 8; ++j) fj[j] = fp[j];

    // B-operand: lane m16 = dim, k = q*8+j. One addr VGPR + imm offsets;
    // 16 lanes x 4B = contiguous 64B segments.
    const float* eb = emb + (size_t)(rb + q * 8) * D_DIM + dimBase + m16;
    float x0[8], x1[8];
    #pragma unroll
    for (int j = 0; j < 8; ++j) {
      x0[j] = eb[j * D_DIM];                 // nt=0: dims dimBase+m16
      x1[j] = eb[j * D_DIM + 16];            // nt=1: dims dimBase+16+m16
    }

    // hi = bit-trunc bf16 (word-packed, 3 ops/word); lo = x - hi (exact),
    // bit-trunc to bf16 (err <= 2^-16 |x|, word-packed 7 ops/word).
    pack8 H0, L0, H1, L1;
    #pragma unroll
    for (int p = 0; p < 4; ++p) {
      unsigned a0 = __float_as_uint(x0[2 * p]);
      unsigned a1 = __float_as_uint(x0[2 * p + 1]);
      H0.u[p] = (a0 >> 16) | (a1 & 0xFFFF0000u);
      float la = x0[2 * p]     - __uint_as_float(a0 & 0xFFFF0000u);
      float lb = x0[2 * p + 1] - __uint_as_float(a1 & 0xFFFF0000u);
      L0.u[p] = (__float_as_uint(la) >> 16) | (__float_as_uint(lb) & 0xFFFF0000u);
      unsigned b0 = __float_as_uint(x1[2 * p]);
      unsigned b1 = __float_as_uint(x1[2 * p + 1]);
      H1.u[p] = (b0 >> 16) | (b1 & 0xFFFF0000u);
      float lc = x1[2 * p]     - __uint_as_float(b0 & 0xFFFF0000u);
      float ld = x1[2 * p + 1] - __uint_as_float(b1 & 0xFFFF0000u);
      L1.u[p] = (__float_as_uint(lc) >> 16) | (__float_as_uint(ld) & 0xFFFF0000u);
    }

    // one-hot A words: elem j = (fam[k]==ft*16+m16) ? 1.0bf16 : 0
    pack8 AF[4];
    #pragma unroll
    for (int ft = 0; ft < 4; ++ft) {
      int tgt = ft * 16 + m16;
      #pragma unroll
      for (int p = 0; p < 4; ++p)
        AF[ft].u[p] = (fj[2 * p] == tgt ? 0x3F80u : 0u) |
                      (fj[2 * p + 1] == tgt ? 0x3F800000u : 0u);
    }

    #pragma unroll
    for (int ft = 0; ft < 4; ++ft) {
      acc[ft][0] = __builtin_amdgcn_mfma_f32_16x16x32_bf16(AF[ft].s, H0.s, acc[ft][0], 0, 0, 0);
      acc[ft][0] = __builtin_amdgcn_mfma_f32_16x16x32_bf16(AF[ft].s, L0.s, acc[ft][0], 0, 0, 0);
      acc[ft][1] = __builtin_amdgcn_mfma_f32_16x16x32_bf16(AF[ft].s, H1.s, acc[ft][1], 0, 0, 0);
      acc[ft][1] = __builtin_amdgcn_mfma_f32_16x16x32_bf16(AF[ft].s, L1.s, acc[ft][1], 0, 0, 0);
    }
  }

  // D[fam = ft*16+q*4+i][dim = dimBase+nt*16+m16]; 16-lane groups = 64B lines
  float* outp = psum + (size_t)blockIdx.x * (F_NUM * D_DIM) + dimBase + m16;
  #pragma unroll
  for (int ft = 0; ft < 4; ++ft)
    #pragma unroll
    for (int i = 0; i < 4; ++i) {
      int f = ft * 16 + q * 4 + i;
      outp[(size_t)f * D_DIM]      = acc[ft][0][i];
      outp[(size_t)f * D_DIM + 16] = acc[ft][1][i];
    }
}

// ---------------- Pass B (fused reduce + normalize + out-zero) ---------------
// 64 blocks x 1024 thr. Block f: thread (d4=t&31, pg=t>>5) sums 32 partials
// of float4 col d4; LDS combine 32 groups; lanes 0..31 normalize + write bf16.
__global__ __launch_bounds__(1024) void pass_b(
    const float* __restrict__ psum, unsigned short* __restrict__ protoB,
    float* __restrict__ out, int nPart)
{
  __shared__ float4 sh[1024];
  int t = threadIdx.x, f = blockIdx.x;
  if (f == 0 && t == 0) out[0] = 0.f;        // stream-ordered before pass_c
  int d4 = t & 31, pg = t >> 5;
  const float4* p4 = (const float4*)psum;    // partial stride 2048 float4
  float4 s = make_float4(0.f, 0.f, 0.f, 0.f);
  int per = nPart >> 5;                      // 32
  #pragma unroll 8
  for (int i = 0; i < per; ++i) {
    float4 a = p4[(size_t)(pg + 32 * i) * (F_NUM * D_DIM / 4) + f * 32 + d4];
    s.x += a.x; s.y += a.y; s.z += a.z; s.w += a.w;
  }
  sh[t] = s;
  __syncthreads();
  if (t < 32) {
    float4 rsum = sh[t];
    #pragma unroll
    for (int g = 1; g < 32; ++g) {
      float4 a = sh[g * 32 + t];
      rsum.x += a.x; rsum.y += a.y; rsum.z += a.z; rsum.w += a.w;
    }
    float n2 = rsum.x * rsum.x + rsum.y * rsum.y +
               rsum.z * rsum.z + rsum.w * rsum.w;
    n2 += __shfl_xor(n2, 1);  n2 += __shfl_xor(n2, 2);  n2 += __shfl_xor(n2, 4);
    n2 += __shfl_xor(n2, 8);  n2 += __shfl_xor(n2, 16);
    float inv = rsqrtf(fmaxf(n2, 1e-24f));   // empty family -> p_hat=0 -> sim=0
    ushort4 u;
    u.x = f2bf(rsum.x * inv); u.y = f2bf(rsum.y * inv);
    u.z = f2bf(rsum.z * inv); u.w = f2bf(rsum.w * inv);
    ((ushort4*)protoB)[f * 32 + t] = u;      // natural [f][128] bf16
  }
}

// ---------------- Pass C -----------------------------------------------------
// N/128 blocks x 256 thr. Wave handles 32 samples (2 st-tiles of 16).
// mfma(A=proto_frag, B=sample_frag): D[f-local q*4+reg][sample m16].
__global__ __launch_bounds__(256) void pass_c(
    const float* __restrict__ emb, const int* __restrict__ fam,
    const unsigned short* __restrict__ protoB,
    float* __restrict__ out, float invN)
{
  __shared__ float sWp[4];
  int t = threadIdx.x, w = t >> 6, lane = t & 63;
  int m16 = lane & 15, q = lane >> 4;
  int S0 = blockIdx.x * 128 + w * 32;

  const float4* E4 = (const float4*)emb;     // row stride 32 float4
  const short8* P8 = (const short8*)protoB;  // row stride 16 chunks

  size_t e0 = (size_t)(S0 + m16) * 32 + q * 2;       // st=0
  size_t e1 = e0 + 16 * 32;                          // st=1
  int pb = m16 * 16 + q;                             // proto frag base (ft=0)

  f32x4 acc[2][4] = {};
  float s2a = 0.f, s2b = 0.f;

  #pragma unroll
  for (int ks = 0; ks < 4; ++ks) {
    short8 a0 = P8[pb + ks * 4];             // protos ft=0 (rows 0..15)
    short8 a1 = P8[pb + 256 + ks * 4];       // ft=1
    short8 a2 = P8[pb + 512 + ks * 4];       // ft=2
    short8 a3 = P8[pb + 768 + ks * 4];       // ft=3

    float4 va = E4[e0 + ks * 8], vb = E4[e0 + ks * 8 + 1];
    s2a += va.x * va.x + va.y * va.y + va.z * va.z + va.w * va.w +
           vb.x * vb.x + vb.y * vb.y + vb.z * vb.z + vb.w * vb.w;
    short8 b0;
    b0[0] = (short)f2bf(va.x); b0[1] = (short)f2bf(va.y);
    b0[2] = (short)f2bf(va.z); b0[3] = (short)f2bf(va.w);
    b0[4] = (short)f2bf(vb.x); b0[5] = (short)f2bf(vb.y);
    b0[6] = (short)f2bf(vb.z); b0[7] = (short)f2bf(vb.w);
    acc[0][0] = __builtin_amdgcn_mfma_f32_16x16x32_bf16(a0, b0, acc[0][0], 0, 0, 0);
    acc[0][1] = __builtin_amdgcn_mfma_f32_16x16x32_bf16(a1, b0, acc[0][1], 0, 0, 0);
    acc[0][2] = __builtin_amdgcn_mfma_f32_16x16x32_bf16(a2, b0, acc[0][2], 0, 0, 0);
    acc[0][3] = __builtin_amdgcn_mfma_f32_16x16x32_bf16(a3, b0, acc[0][3], 0, 0, 0);

    float4 vc = E4[e1 + ks * 8], vd = E4[e1 + ks * 8 + 1];
    s2b += vc.x * vc.x + vc.y * vc.y + vc.z * vc.z + vc.w * vc.w +
           vd.x * vd.x + vd.y * vd.y + vd.z * vd.z + vd.w * vd.w;
    short8 b1;
    b1[0] = (short)f2bf(vc.x); b1[1] = (short)f2bf(vc.y);
    b1[2] = (short)f2bf(vc.z); b1[3] = (short)f2bf(vc.w);
    b1[4] = (short)f2bf(vd.x); b1[5] = (short)f2bf(vd.y);
    b1[6] = (short)f2bf(vd.z); b1[7] = (short)f2bf(vd.w);
    acc[1][0] = __builtin_amdgcn_mfma_f32_16x16x32_bf16(a0, b1, acc[1][0], 0, 0, 0);
    acc[1][1] = __builtin_amdgcn_mfma_f32_16x16x32_bf16(a1, b1, acc[1][1], 0, 0, 0);
    acc[1][2] = __builtin_amdgcn_mfma_f32_16x16x32_bf16(a2, b1, acc[1][2], 0, 0, 0);
    acc[1][3] = __builtin_amdgcn_mfma_f32_16x16x32_bf16(a3, b1, acc[1][3], 0, 0, 0);
  }

  // per-sample norms: lane covers dims {ks*32+q*8..+8}; q-reduce completes 128
  s2a += __shfl_xor(s2a, 16); s2a += __shfl_xor(s2a, 32);
  s2b += __shfl_xor(s2b, 16); s2b += __shfl_xor(s2b, 32);
  float rn0 = rsqrtf(fmaxf(s2a, 1e-20f));
  float rn1 = rsqrtf(fmaxf(s2b, 1e-20f));
  int fr0 = fam[S0 + m16], fr1 = fam[S0 + 16 + m16];

  float wp = 0.f;
  {
    int fh = fr0 >> 4, fq = (fr0 >> 2) & 3, fl = fr0 & 3;
    float es = 0.f, ps = 0.f;
    #pragma unroll
    for (int ft = 0; ft < 4; ++ft)
      #pragma unroll
      for (int i = 0; i < 4; ++i) {
        float sim = acc[0][ft][i] * rn0;     // f = ft*16 + q*4 + i
        es += __expf(4.f * sim - 4.f);       // arg in [-8, ~0]
        ps += (fq == q && fh == ft && fl == i) ? sim : 0.f;
      }
    es += __shfl_xor(es, 16); es += __shfl_xor(es, 32);
    ps += __shfl_xor(ps, 16); ps += __shfl_xor(ps, 32);
    if (q == 0) wp += 4.f + __logf(es) - 2.f * ps;
  }
  {
    int fh = fr1 >> 4, fq = (fr1 >> 2) & 3, fl = fr1 & 3;
    float es = 0.f, ps = 0.f;
    #pragma unroll
    for (int ft = 0; ft < 4; ++ft)
      #pragma unroll
      for (int i = 0; i < 4; ++i) {
        float sim = acc[1][ft][i] * rn1;
        es += __expf(4.f * sim - 4.f);
        ps += (fq == q && fh == ft && fl == i) ? sim : 0.f;
      }
    es += __shfl_xor(es, 16); es += __shfl_xor(es, 32);
    ps += __shfl_xor(ps, 16); ps += __shfl_xor(ps, 32);
    if (q == 0) wp += 4.f + __logf(es) - 2.f * ps;
  }

  // wave total (q!=0 lanes hold 0)
  wp += __shfl_xor(wp, 1);  wp += __shfl_xor(wp, 2);  wp += __shfl_xor(wp, 4);
  wp += __shfl_xor(wp, 8);  wp += __shfl_xor(wp, 16); wp += __shfl_xor(wp, 32);
  if (lane == 0) sWp[w] = wp;
  __syncthreads();
  if (t == 0)
    unsafeAtomicAdd(out, (sWp[0] + sWp[1] + sWp[2] + sWp[3]) * invN);
}

extern "C" void kernel_launch(void* const* d_in, const int* in_sizes, int n_in,
                              void* d_out, int out_size, void* d_ws, size_t ws_size,
                              hipStream_t stream) {
  const float* emb = (const float*)d_in[0];
  const int* fam = (const int*)d_in[1];
  int N = in_sizes[0] / D_DIM;               // 262144
  int blocksA = N / ROWS_A;                  // 1024
  int blocksC = N / 128;                     // 2048

  // ws (float units): psum[1024*8192] | protoB(8192 ushort)
  float* ws = (float*)d_ws;
  float* psum = ws;
  size_t off = (size_t)blocksA * (F_NUM * D_DIM);
  unsigned short* protoB = (unsigned short*)(ws + off);

  pass_a<<<blocksA, 256, 0, stream>>>(emb, fam, psum);
  pass_b<<<F_NUM, 1024, 0, stream>>>(psum, protoB, (float*)d_out, blocksA);
  pass_c<<<blocksC, 256, 0, stream>>>(emb, fam, protoB, (float*)d_out,
                                      1.0f / (float)N);
}

// Round 8
// 246.512 us; speedup vs baseline: 1.0202x; 1.0202x over previous
//
#include <hip/hip_runtime.h>
#include <math.h>

// ProtoLoss: loss = mean_n( -2*sim[n,fam[n]] + logsumexp_f(4*sim[n,f]) )
// sim = (e.p)/(||e||*||p||) -- scale-invariant in p: p_hat = raw_sum/||raw_sum||.
// N=262144, D=128, F=64.
//
// Session ledger:
//  - LDS fp32 atomics: ~0.3 lane-ops/cyc/CU -> per-element-atomic segment sum
//    floors at ~150us (r1/r3).
//  - Two 512MB harness poison-fills (~78us each) sit INSIDE the timed window:
//    ~156us of dur_us is untouchable (r0/r5/r6 top-5).
//  - Segment-sum-as-MFMA with one-hot A (bf16-exact) + hi/lo bf16 split of
//    emb (hi=trunc, lo=RNE(x-hi)) is fp32-exact to ~2^-17: absmax 0.0 (r4/r5).
//  - Keep MFMA accumulator <= 32 VGPRs (r4: acc[4][8] spilled, 301MB scratch).
//  - No __launch_bounds__ min-wave floor beyond the live set (r6: (256,4)
//    capped VGPR at 128 -> spill -> +16us).
//  - NO hipLaunchCooperativeKernel in this harness (r7: container death --
//    graph-capture and/or grid.sync co-residency deadlock).
//  - Same-address per-block f32 atomic at kernel end is free (r1->r2 A/B).
//
// Structure (r5, best measured 235.1us, minus pass_d):
// A) 512 blocks x 256 thr (2 blk/CU). Wave w owns dim-slice [32w,+32) for the
//    block's 512 rows -> acc[4][2] = 32 VGPRs, register-resident, no LDS,
//    no barrier. Per 32-row K-slab: 8 fam dwords, one-hot A-frags, emb
//    gathers (64B segments), hi/lo bf16 split, 16 MFMA. Direct reg->psum.
// B) 64 blocks x 256 thr: reduce 512 partials + normalize -> protoB bf16;
//    block 0 zeroes d_out (stream-ordered before pass_c).
// C) 2048 blocks x 256 thr: swapped-operand MFMA sims + fused lse epilogue;
//    one unsafeAtomicAdd per block.

#define D_DIM 128
#define F_NUM 64
#define ROWS_A 512

typedef __attribute__((ext_vector_type(8))) short short8;
typedef __attribute__((ext_vector_type(4))) float f32x4;

static __device__ __forceinline__ unsigned short f2bf(float x) {
  union { float f; unsigned u; } v; v.f = x;
  unsigned r = v.u + 0x7FFFu + ((v.u >> 16) & 1u);   // RNE
  return (unsigned short)(r >> 16);
}

// ---------------- Pass A -----------------------------------------------------
__global__ __launch_bounds__(256, 2) void pass_a(
    const float* __restrict__ emb, const int* __restrict__ fam,
    float* __restrict__ psum)
{
  int t = threadIdx.x, w = t >> 6, lane = t & 63;
  int m16 = lane & 15, q = lane >> 4;
  int dimBase = w * 32;                      // wave's private dim slice

  f32x4 acc[4][2] = {};                      // [f-tile][dim-tile] = 32 VGPRs
  int rb0 = blockIdx.x * ROWS_A;

  #pragma unroll 2
  for (int s = 0; s < ROWS_A / 32; ++s) {
    int rb = rb0 + s * 32;                   // K-slab of 32 rows
    // fam for this lane's k-slots: k = q*8 + j (verified A convention)
    const int* fp = fam + rb + q * 8;
    int fj[8];
    #pragma unroll
    for (int j = 0; j < 8; ++j) fj[j] = fp[j];

    // B-operand: lane m16 = dim, k = q*8+j. One addr VGPR + imm offsets;
    // 16 lanes x 4B = contiguous 64B segments.
    const float* eb = emb + (size_t)(rb + q * 8) * D_DIM + dimBase + m16;
    float x0[8], x1[8];
    #pragma unroll
    for (int j = 0; j < 8; ++j) {
      x0[j] = eb[j * D_DIM];                 // nt=0: dims dimBase+m16
      x1[j] = eb[j * D_DIM + 16];            // nt=1: dims dimBase+16+m16
    }

    // one-hot A-frags: A[m16][k] = (fam[k] == ft*16+m16) ? 1.0bf16 : 0
    short8 af[4];
    #pragma unroll
    for (int ft = 0; ft < 4; ++ft)
      #pragma unroll
      for (int j = 0; j < 8; ++j)
        af[ft][j] = (fj[j] == ft * 16 + m16) ? (short)0x3F80 : (short)0;

    short8 h0, l0, h1, l1;                   // hi = truncate, lo = RNE(x-hi)
    #pragma unroll
    for (int j = 0; j < 8; ++j) {
      unsigned b0 = __float_as_uint(x0[j]);
      h0[j] = (short)(b0 >> 16);
      l0[j] = (short)f2bf(x0[j] - __uint_as_float(b0 & 0xFFFF0000u));
      unsigned b1 = __float_as_uint(x1[j]);
      h1[j] = (short)(b1 >> 16);
      l1[j] = (short)f2bf(x1[j] - __uint_as_float(b1 & 0xFFFF0000u));
    }

    #pragma unroll
    for (int ft = 0; ft < 4; ++ft) {
      acc[ft][0] = __builtin_amdgcn_mfma_f32_16x16x32_bf16(af[ft], h0, acc[ft][0], 0, 0, 0);
      acc[ft][0] = __builtin_amdgcn_mfma_f32_16x16x32_bf16(af[ft], l0, acc[ft][0], 0, 0, 0);
      acc[ft][1] = __builtin_amdgcn_mfma_f32_16x16x32_bf16(af[ft], h1, acc[ft][1], 0, 0, 0);
      acc[ft][1] = __builtin_amdgcn_mfma_f32_16x16x32_bf16(af[ft], l1, acc[ft][1], 0, 0, 0);
    }
  }

  // D[fam = ft*16+q*4+i][dim = dimBase+nt*16+m16]; 16-lane groups = 64B lines
  float* outp = psum + (size_t)blockIdx.x * (F_NUM * D_DIM) + dimBase + m16;
  #pragma unroll
  for (int ft = 0; ft < 4; ++ft)
    #pragma unroll
    for (int i = 0; i < 4; ++i) {
      int f = ft * 16 + q * 4 + i;
      outp[(size_t)f * D_DIM]      = acc[ft][0][i];
      outp[(size_t)f * D_DIM + 16] = acc[ft][1][i];
    }
}

// ---------------- Pass B (fused reduce + normalize + out-zero) ---------------
// 64 blocks x 256 thr. Block f: thread (d4=t&31, pg=t>>5) sums 64 partials of
// float4 col d4; LDS combine 8 groups; lanes 0..31 normalize + write bf16 row.
__global__ __launch_bounds__(256) void pass_b(
    const float* __restrict__ psum, unsigned short* __restrict__ protoB,
    float* __restrict__ out, int nPart)
{
  __shared__ float4 sh[256];
  int t = threadIdx.x, f = blockIdx.x;
  if (f == 0 && t == 0) out[0] = 0.f;        // stream-ordered before pass_c
  int d4 = t & 31, pg = t >> 5;
  const float4* p4 = (const float4*)psum;    // partial stride 2048 float4
  float4 s = make_float4(0.f, 0.f, 0.f, 0.f);
  int per = nPart >> 3;                      // 64
  #pragma unroll 8
  for (int i = 0; i < per; ++i) {
    float4 a = p4[(size_t)(pg + 8 * i) * (F_NUM * D_DIM / 4) + f * 32 + d4];
    s.x += a.x; s.y += a.y; s.z += a.z; s.w += a.w;
  }
  sh[t] = s;
  __syncthreads();
  if (t < 32) {
    float4 rsum = sh[t];
    #pragma unroll
    for (int g = 1; g < 8; ++g) {
      float4 a = sh[g * 32 + t];
      rsum.x += a.x; rsum.y += a.y; rsum.z += a.z; rsum.w += a.w;
    }
    float n2 = rsum.x * rsum.x + rsum.y * rsum.y +
               rsum.z * rsum.z + rsum.w * rsum.w;
    n2 += __shfl_xor(n2, 1);  n2 += __shfl_xor(n2, 2);  n2 += __shfl_xor(n2, 4);
    n2 += __shfl_xor(n2, 8);  n2 += __shfl_xor(n2, 16);
    float inv = rsqrtf(fmaxf(n2, 1e-24f));   // empty family -> p_hat=0 -> sim=0
    ushort4 u;
    u.x = f2bf(rsum.x * inv); u.y = f2bf(rsum.y * inv);
    u.z = f2bf(rsum.z * inv); u.w = f2bf(rsum.w * inv);
    ((ushort4*)protoB)[f * 32 + t] = u;      // natural [f][128] bf16
  }
}

// ---------------- Pass C -----------------------------------------------------
// N/128 blocks x 256 thr. Wave handles 32 samples (2 st-tiles of 16).
// mfma(A=proto_frag, B=sample_frag): D[f-local q*4+reg][sample m16].
__global__ __launch_bounds__(256) void pass_c(
    const float* __restrict__ emb, const int* __restrict__ fam,
    const unsigned short* __restrict__ protoB,
    float* __restrict__ out, float invN)
{
  __shared__ float sWp[4];
  int t = threadIdx.x, w = t >> 6, lane = t & 63;
  int m16 = lane & 15, q = lane >> 4;
  int S0 = blockIdx.x * 128 + w * 32;

  const float4* E4 = (const float4*)emb;     // row stride 32 float4
  const short8* P8 = (const short8*)protoB;  // row stride 16 chunks

  size_t e0 = (size_t)(S0 + m16) * 32 + q * 2;       // st=0
  size_t e1 = e0 + 16 * 32;                          // st=1
  int pb = m16 * 16 + q;                             // proto frag base (ft=0)

  f32x4 acc[2][4] = {};
  float s2a = 0.f, s2b = 0.f;

  #pragma unroll
  for (int ks = 0; ks < 4; ++ks) {
    short8 a0 = P8[pb + ks * 4];             // protos ft=0 (rows 0..15)
    short8 a1 = P8[pb + 256 + ks * 4];       // ft=1
    short8 a2 = P8[pb + 512 + ks * 4];       // ft=2
    short8 a3 = P8[pb + 768 + ks * 4];       // ft=3

    float4 va = E4[e0 + ks * 8], vb = E4[e0 + ks * 8 + 1];
    s2a += va.x * va.x + va.y * va.y + va.z * va.z + va.w * va.w +
           vb.x * vb.x + vb.y * vb.y + vb.z * vb.z + vb.w * vb.w;
    short8 b0;
    b0[0] = (short)f2bf(va.x); b0[1] = (short)f2bf(va.y);
    b0[2] = (short)f2bf(va.z); b0[3] = (short)f2bf(va.w);
    b0[4] = (short)f2bf(vb.x); b0[5] = (short)f2bf(vb.y);
    b0[6] = (short)f2bf(vb.z); b0[7] = (short)f2bf(vb.w);
    acc[0][0] = __builtin_amdgcn_mfma_f32_16x16x32_bf16(a0, b0, acc[0][0], 0, 0, 0);
    acc[0][1] = __builtin_amdgcn_mfma_f32_16x16x32_bf16(a1, b0, acc[0][1], 0, 0, 0);
    acc[0][2] = __builtin_amdgcn_mfma_f32_16x16x32_bf16(a2, b0, acc[0][2], 0, 0, 0);
    acc[0][3] = __builtin_amdgcn_mfma_f32_16x16x32_bf16(a3, b0, acc[0][3], 0, 0, 0);

    float4 vc = E4[e1 + ks * 8], vd = E4[e1 + ks * 8 + 1];
    s2b += vc.x * vc.x + vc.y * vc.y + vc.z * vc.z + vc.w * vc.w +
           vd.x * vd.x + vd.y * vd.y + vd.z * vd.z + vd.w * vd.w;
    short8 b1;
    b1[0] = (short)f2bf(vc.x); b1[1] = (short)f2bf(vc.y);
    b1[2] = (short)f2bf(vc.z); b1[3] = (short)f2bf(vc.w);
    b1[4] = (short)f2bf(vd.x); b1[5] = (short)f2bf(vd.y);
    b1[6] = (short)f2bf(vd.z); b1[7] = (short)f2bf(vd.w);
    acc[1][0] = __builtin_amdgcn_mfma_f32_16x16x32_bf16(a0, b1, acc[1][0], 0, 0, 0);
    acc[1][1] = __builtin_amdgcn_mfma_f32_16x16x32_bf16(a1, b1, acc[1][1], 0, 0, 0);
    acc[1][2] = __builtin_amdgcn_mfma_f32_16x16x32_bf16(a2, b1, acc[1][2], 0, 0, 0);
    acc[1][3] = __builtin_amdgcn_mfma_f32_16x16x32_bf16(a3, b1, acc[1][3], 0, 0, 0);
  }

  // per-sample norms: lane covers dims {ks*32+q*8..+8}; q-reduce completes 128
  s2a += __shfl_xor(s2a, 16); s2a += __shfl_xor(s2a, 32);
  s2b += __shfl_xor(s2b, 16); s2b += __shfl_xor(s2b, 32);
  float rn0 = rsqrtf(fmaxf(s2a, 1e-20f));
  float rn1 = rsqrtf(fmaxf(s2b, 1e-20f));
  int fr0 = fam[S0 + m16], fr1 = fam[S0 + 16 + m16];

  float wp = 0.f;
  {
    int fh = fr0 >> 4, fq = (fr0 >> 2) & 3, fl = fr0 & 3;
    float es = 0.f, ps = 0.f;
    #pragma unroll
    for (int ft = 0; ft < 4; ++ft)
      #pragma unroll
      for (int i = 0; i < 4; ++i) {
        float sim = acc[0][ft][i] * rn0;     // f = ft*16 + q*4 + i
        es += __expf(4.f * sim - 4.f);       // arg in [-8, ~0]
        ps += (fq == q && fh == ft && fl == i) ? sim : 0.f;
      }
    es += __shfl_xor(es, 16); es += __shfl_xor(es, 32);
    ps += __shfl_xor(ps, 16); ps += __shfl_xor(ps, 32);
    if (q == 0) wp += 4.f + __logf(es) - 2.f * ps;
  }
  {
    int fh = fr1 >> 4, fq = (fr1 >> 2) & 3, fl = fr1 & 3;
    float es = 0.f, ps = 0.f;
    #pragma unroll
    for (int ft = 0; ft < 4; ++ft)
      #pragma unroll
      for (int i = 0; i < 4; ++i) {
        float sim = acc[1][ft][i] * rn1;
        es += __expf(4.f * sim - 4.f);
        ps += (fq == q && fh == ft && fl == i) ? sim : 0.f;
      }
    es += __shfl_xor(es, 16); es += __shfl_xor(es, 32);
    ps += __shfl_xor(ps, 16); ps += __shfl_xor(ps, 32);
    if (q == 0) wp += 4.f + __logf(es) - 2.f * ps;
  }

  // wave total (q!=0 lanes hold 0)
  wp += __shfl_xor(wp, 1);  wp += __shfl_xor(wp, 2);  wp += __shfl_xor(wp, 4);
  wp += __shfl_xor(wp, 8);  wp += __shfl_xor(wp, 16); wp += __shfl_xor(wp, 32);
  if (lane == 0) sWp[w] = wp;
  __syncthreads();
  if (t == 0)
    unsafeAtomicAdd(out, (sWp[0] + sWp[1] + sWp[2] + sWp[3]) * invN);
}

extern "C" void kernel_launch(void* const* d_in, const int* in_sizes, int n_in,
                              void* d_out, int out_size, void* d_ws, size_t ws_size,
                              hipStream_t stream) {
  const float* emb = (const float*)d_in[0];
  const int* fam = (const int*)d_in[1];
  int N = in_sizes[0] / D_DIM;               // 262144
  int blocksA = N / ROWS_A;                  // 512
  int blocksC = N / 128;                     // 2048

  // ws (float units): psum[512*8192] | protoB(8192 ushort)
  float* ws = (float*)d_ws;
  float* psum = ws;
  unsigned short* protoB = (unsigned short*)(ws + (size_t)blocksA * (F_NUM * D_DIM));

  pass_a<<<blocksA, 256, 0, stream>>>(emb, fam, psum);
  pass_b<<<F_NUM, 256, 0, stream>>>(psum, protoB, (float*)d_out, blocksA);
  pass_c<<<blocksC, 256, 0, stream>>>(emb, fam, protoB, (float*)d_out,
                                      1.0f / (float)N);
}